// Round 11
// baseline (470.019 us; speedup 1.0000x reference)
//
#include <hip/hip_runtime.h>
#include <math.h>

#define DDIM 1024
#define NCH 64
#define LSEQ 4096
#define NBATCH 8
#define NROWS (NBATCH * LSEQ)   // 32768
#define EPSF 1e-6f
#define NCK 256                 // chunks per sequence
#define CLEN 16                 // timesteps per chunk (NCK*CLEN == LSEQ)
#define NM ((size_t)NROWS * NCH)
#define SC ((size_t)NBATCH * NCK * NCH)

__device__ __forceinline__ float softplusf(float v) {
    return (v > 20.0f) ? v : log1pf(expf(v));
}

// ---------------- prep: WoT[n][d] = Wo[d][n] ----------------
__global__ void prep_kernel(const float* __restrict__ Wo, float* __restrict__ WoT) {
    int id = blockIdx.x * 256 + threadIdx.x;
    int n = id >> 10;
    int d = id & (DDIM - 1);
    WoT[n * DDIM + d] = Wo[d * NCH + n];
}

// ---------------- proj2: 4-way K-split GEMM, W from L2, partials to 4 buffers ----
// Grid = (NROWS/128)*4.  rt = bid>>2, ks = bid&3 (K quarter: 256 each).
#define MT 128
#define KSPL 4
#define KRNG (DDIM / KSPL)      // 256
#define SUBK 32

__global__ __launch_bounds__(256, 4) void proj2_kernel(
        const float* __restrict__ x,
        const float* __restrict__ WB,
        const float* __restrict__ Wd,
        float* __restrict__ Part,     // 4 x NM partial B_t
        float* __restrict__ DeAll) {  // 4 x NROWS partial Delta
    __shared__ float x_lds[MT][36];
    const int t  = threadIdx.x;
    const int tr = t & 31;
    const int tc = t >> 5;
    const int rt = blockIdx.x >> 2;
    const int ks = blockIdx.x & 3;
    const int R0 = rt * MT;
    const int kb0 = ks * KRNG;

    float acc[4][8];
    #pragma unroll
    for (int i = 0; i < 4; i++)
        #pragma unroll
        for (int j = 0; j < 8; j++) acc[i][j] = 0.0f;
    float dpart = 0.0f;

    for (int kk = 0; kk < KRNG; kk += SUBK) {
        const int kb = kb0 + kk;
        __syncthreads();
        #pragma unroll
        for (int p = 0; p < 4; p++) {
            const int row = p * 32 + (t >> 3);
            const int c   = (t & 7) * 4;
            const float4 v = *reinterpret_cast<const float4*>(
                &x[(size_t)(R0 + row) * DDIM + kb + c]);
            *reinterpret_cast<float4*>(&x_lds[row][c]) = v;
        }
        __syncthreads();

        if (t < MT) {
            #pragma unroll 8
            for (int k = 0; k < SUBK; k++)
                dpart = fmaf(x_lds[t][k], Wd[kb + k], dpart);
        }

        #pragma unroll
        for (int k4 = 0; k4 < SUBK / 4; k4++) {
            float4 wv[8];
            #pragma unroll
            for (int j = 0; j < 8; j++)
                wv[j] = *reinterpret_cast<const float4*>(
                    &WB[(size_t)(tc * 8 + j) * DDIM + kb + k4 * 4]);
            float4 xv[4];
            #pragma unroll
            for (int i = 0; i < 4; i++)
                xv[i] = *reinterpret_cast<const float4*>(&x_lds[tr + 32 * i][k4 * 4]);
            #pragma unroll
            for (int i = 0; i < 4; i++)
                #pragma unroll
                for (int j = 0; j < 8; j++) {
                    acc[i][j] = fmaf(xv[i].x, wv[j].x, acc[i][j]);
                    acc[i][j] = fmaf(xv[i].y, wv[j].y, acc[i][j]);
                    acc[i][j] = fmaf(xv[i].z, wv[j].z, acc[i][j]);
                    acc[i][j] = fmaf(xv[i].w, wv[j].w, acc[i][j]);
                }
        }
    }

    float* Bt = Part + (size_t)ks * NM;
    #pragma unroll
    for (int i = 0; i < 4; i++) {
        const size_t base = (size_t)(R0 + tr + 32 * i) * NCH + tc * 8;
        *reinterpret_cast<float4*>(&Bt[base])     = make_float4(acc[i][0], acc[i][1], acc[i][2], acc[i][3]);
        *reinterpret_cast<float4*>(&Bt[base + 4]) = make_float4(acc[i][4], acc[i][5], acc[i][6], acc[i][7]);
    }
    if (t < MT) DeAll[(size_t)ks * NROWS + R0 + t] = dpart;
}

// ---------------- gate: sum 4 partials + softplus/exp epilogue ----------------
// grid = NROWS/4, block 256. Part[0] -> dB in place; Part[1] -> dA in place.
__global__ __launch_bounds__(256) void gate_kernel(
        const float* __restrict__ A_log, const float* __restrict__ bB,
        const float* __restrict__ bd,
        const float* __restrict__ DeAll,
        float* __restrict__ Part) {
    const int t   = threadIdx.x;
    const int n   = t & 63;
    const int row = blockIdx.x * 4 + (t >> 6);
    const size_t idx = (size_t)row * NCH + n;
    const float a   = -softplusf(A_log[n]);
    const float dsum = DeAll[row] + DeAll[NROWS + row]
                     + DeAll[2 * (size_t)NROWS + row] + DeAll[3 * (size_t)NROWS + row];
    const float dlt = softplusf(dsum + bd[0]);
    const float Btv = Part[idx] + Part[idx + NM] + Part[idx + 2 * NM] + Part[idx + 3 * NM] + bB[n];
    const float dAv = expf(a * dlt);
    const float dBv = (dAv - 1.0f) / (a + EPSF) * Btv;
    Part[idx + NM] = dAv;   // dA
    Part[idx]      = dBv;   // dB
}

// ---------------- chunked scan, 3 phases (NCK=256, CLEN=16) ----------------
__global__ __launch_bounds__(64) void chunkprod_kernel(
        const float* __restrict__ dA_g, float* __restrict__ P) {
    const int n = threadIdx.x;
    const int blk = blockIdx.x;
    size_t base = (size_t)blk * CLEN * NCH + n;
    float p = 1.0f;
    #pragma unroll
    for (int u = 0; u < CLEN; u++) p *= dA_g[base + (size_t)u * NCH];
    P[(size_t)blk * NCH + n] = p;
}

// grid 8 (one per batch), 64 threads (n); 16-batched serial product scan
__global__ __launch_bounds__(64) void stitch1_kernel(
        const float* __restrict__ P, float* __restrict__ E) {
    const int b = blockIdx.x, n = threadIdx.x;
    size_t idx = (size_t)b * NCK * NCH + n;
    float e = 1.0f;
    for (int j0 = 0; j0 < NCK; j0 += 16) {
        float p16[16];
        #pragma unroll
        for (int u = 0; u < 16; u++) p16[u] = P[idx + (size_t)(j0 + u) * NCH];
        #pragma unroll
        for (int u = 0; u < 16; u++) {
            E[idx + (size_t)(j0 + u) * NCH] = e;
            e *= p16[u];
        }
    }
}

__global__ __launch_bounds__(64) void chunkz_kernel(
        const float* __restrict__ dA_g, const float* __restrict__ dB_g,
        const float* __restrict__ E, float* __restrict__ Z) {
    const int n = threadIdx.x;
    const int blk = blockIdx.x;
    size_t base = (size_t)blk * CLEN * NCH + n;
    const float e = E[(size_t)blk * NCH + n];
    float L = 1.0f, zs = 0.0f;
    #pragma unroll
    for (int u = 0; u < CLEN; u++) {
        const float a  = dA_g[base + (size_t)u * NCH];
        const float bv = dB_g[base + (size_t)u * NCH];
        const float c  = e * L;
        zs += bv / (c + EPSF);
        L *= a;
    }
    Z[(size_t)blk * NCH + n] = zs;
}

__global__ __launch_bounds__(64) void stitch2_kernel(
        const float* __restrict__ Z, float* __restrict__ S) {
    const int b = blockIdx.x, n = threadIdx.x;
    size_t idx = (size_t)b * NCK * NCH + n;
    float s = 0.0f;
    for (int j0 = 0; j0 < NCK; j0 += 16) {
        float z16[16];
        #pragma unroll
        for (int u = 0; u < 16; u++) z16[u] = Z[idx + (size_t)(j0 + u) * NCH];
        #pragma unroll
        for (int u = 0; u < 16; u++) {
            S[idx + (size_t)(j0 + u) * NCH] = s;
            s += z16[u];
        }
    }
}

__global__ __launch_bounds__(64) void chunkout_kernel(
        const float* __restrict__ dA_g, float* __restrict__ dBG,
        const float* __restrict__ E, const float* __restrict__ S) {
    const int n = threadIdx.x;
    const int blk = blockIdx.x;
    size_t base = (size_t)blk * CLEN * NCH + n;
    const float e = E[(size_t)blk * NCH + n];
    float L = 1.0f;
    float s = S[(size_t)blk * NCH + n];
    #pragma unroll
    for (int u = 0; u < CLEN; u++) {
        const float a  = dA_g[base + (size_t)u * NCH];
        const float bv = dBG [base + (size_t)u * NCH];
        const float c  = e * L;
        s += bv / (c + EPSF);
        dBG[base + (size_t)u * NCH] = c * c * s;
        L *= a;
    }
}

// ---------------- out2: Y = G @ WoT + bo, 8x8/thread, WoT from L2 ----------------
__global__ __launch_bounds__(256, 4) void out2_kernel(
        const float* __restrict__ G,
        const float* __restrict__ WoT,
        const float* __restrict__ bo,
        float* __restrict__ Y) {
    __shared__ float g_lds[NCH][36];
    const int t  = threadIdx.x;
    const int tc = t & 63;
    const int tr = t >> 6;
    const int R0 = (blockIdx.x >> 1) * 32;
    const int D0 = (blockIdx.x & 1) * 512;

    {
        const int grow = t >> 3;
        const int gn0  = (t & 7) * 8;
        const float4 a0 = *reinterpret_cast<const float4*>(&G[(size_t)(R0 + grow) * NCH + gn0]);
        const float4 a1 = *reinterpret_cast<const float4*>(&G[(size_t)(R0 + grow) * NCH + gn0 + 4]);
        g_lds[gn0 + 0][grow] = a0.x; g_lds[gn0 + 1][grow] = a0.y;
        g_lds[gn0 + 2][grow] = a0.z; g_lds[gn0 + 3][grow] = a0.w;
        g_lds[gn0 + 4][grow] = a1.x; g_lds[gn0 + 5][grow] = a1.y;
        g_lds[gn0 + 6][grow] = a1.z; g_lds[gn0 + 7][grow] = a1.w;
    }
    __syncthreads();

    float acc[8][8];
    #pragma unroll
    for (int i = 0; i < 8; i++)
        #pragma unroll
        for (int j = 0; j < 8; j++) acc[i][j] = 0.0f;

    const size_t wcol = (size_t)D0 + tc * 8;
    for (int n = 0; n < NCH; n++) {
        const float4 g0 = *reinterpret_cast<const float4*>(&g_lds[n][tr * 8]);
        const float4 g1 = *reinterpret_cast<const float4*>(&g_lds[n][tr * 8 + 4]);
        const float4 w0 = *reinterpret_cast<const float4*>(&WoT[(size_t)n * DDIM + wcol]);
        const float4 w1 = *reinterpret_cast<const float4*>(&WoT[(size_t)n * DDIM + wcol + 4]);
        const float ga[8] = {g0.x, g0.y, g0.z, g0.w, g1.x, g1.y, g1.z, g1.w};
        const float wa[8] = {w0.x, w0.y, w0.z, w0.w, w1.x, w1.y, w1.z, w1.w};
        #pragma unroll
        for (int i = 0; i < 8; i++)
            #pragma unroll
            for (int j = 0; j < 8; j++)
                acc[i][j] = fmaf(ga[i], wa[j], acc[i][j]);
    }

    const float4 b0 = *reinterpret_cast<const float4*>(&bo[wcol]);
    const float4 b1 = *reinterpret_cast<const float4*>(&bo[wcol + 4]);
    #pragma unroll
    for (int i = 0; i < 8; i++) {
        const size_t yb = (size_t)(R0 + tr * 8 + i) * DDIM + wcol;
        *reinterpret_cast<float4*>(&Y[yb]) =
            make_float4(acc[i][0] + b0.x, acc[i][1] + b0.y, acc[i][2] + b0.z, acc[i][3] + b0.w);
        *reinterpret_cast<float4*>(&Y[yb + 4]) =
            make_float4(acc[i][4] + b1.x, acc[i][5] + b1.y, acc[i][6] + b1.z, acc[i][7] + b1.w);
    }
}

extern "C" void kernel_launch(void* const* d_in, const int* in_sizes, int n_in,
                              void* d_out, int out_size, void* d_ws, size_t ws_size,
                              hipStream_t stream) {
    const float* x     = (const float*)d_in[0];
    const float* A_log = (const float*)d_in[1];
    const float* WB    = (const float*)d_in[2];
    const float* bB    = (const float*)d_in[3];
    const float* Wd    = (const float*)d_in[6];
    const float* bd    = (const float*)d_in[7];
    const float* Wo    = (const float*)d_in[8];
    const float* bo    = (const float*)d_in[9];
    float* Y = (float*)d_out;

    float* Part = (float*)d_ws;                    // 4 x NM (partial Bt; [0]->dB->G, [1]->dA)
    float* dBG  = Part;                            // alias partial 0
    float* dA_g = Part + NM;                       // alias partial 1
    float* WoT  = Part + 4 * NM;                   // NCH*DDIM
    float* P    = WoT + (size_t)NCH * DDIM;        // SC
    float* E    = P + SC;
    float* Z    = E + SC;
    float* S    = Z + SC;
    float* DeAll = S + SC;                         // 4 x NROWS

    const int NCHUNKS = NBATCH * NCK;              // 2048

    prep_kernel<<<dim3(256), dim3(256), 0, stream>>>(Wo, WoT);
    proj2_kernel<<<dim3((NROWS / MT) * KSPL), dim3(256), 0, stream>>>(
        x, WB, Wd, Part, DeAll);
    gate_kernel<<<dim3(NROWS / 4), dim3(256), 0, stream>>>(
        A_log, bB, bd, DeAll, Part);
    chunkprod_kernel<<<dim3(NCHUNKS), dim3(64), 0, stream>>>(dA_g, P);
    stitch1_kernel<<<dim3(NBATCH), dim3(64), 0, stream>>>(P, E);
    chunkz_kernel<<<dim3(NCHUNKS), dim3(64), 0, stream>>>(dA_g, dBG, E, Z);
    stitch2_kernel<<<dim3(NBATCH), dim3(64), 0, stream>>>(Z, S);
    chunkout_kernel<<<dim3(NCHUNKS), dim3(64), 0, stream>>>(dA_g, dBG, E, S);
    out2_kernel<<<dim3((NROWS / 32) * 2), dim3(256), 0, stream>>>(dBG, WoT, bo, Y);
}